// Round 4
// baseline (9148.326 us; speedup 1.0000x reference)
//
#include <hip/hip_runtime.h>

#define NN 50000
#define NE 600000
#define DIM 128
#define NLAYERS 8
#define NCLASSES 10
#define NGRAPHS 64
#define BN_EPS 1e-5f
#define SLOPE 0.01f

__device__ __forceinline__ float lrelu(float v) { return v > 0.f ? v : SLOPE * v; }

// ---------------- scatter: agg[dst] += h[src], one thread per (edge, float4-chunk)
__global__ __launch_bounds__(256) void scatter_kernel(const float* __restrict__ h,
                                                      const int* __restrict__ edges,
                                                      float* __restrict__ agg) {
    long long gid = (long long)blockIdx.x * blockDim.x + threadIdx.x;
    if (gid >= (long long)NE * 32) return;
    int e = (int)(gid >> 5);
    int chunk = (int)(gid & 31);
    int s = edges[e];
    int d = edges[NE + e];
    float4 v = *(const float4*)(h + (long long)s * DIM + chunk * 4);
    float* p = agg + (long long)d * DIM + chunk * 4;
    atomicAdd(p + 0, v.x);
    atomicAdd(p + 1, v.y);
    atomicAdd(p + 2, v.z);
    atomicAdd(p + 3, v.w);
}

// ---------------- fused GEMM: C = act( (A (+ Hadd)) @ W + b ),  A:[NN,128] W:[128,128]
// block: 256 threads, tile 32 rows x 128 cols, 16 outputs/thread
template <int ACT, int USEADD>
__global__ __launch_bounds__(256) void gemm_fused(const float* __restrict__ A,
                                                  const float* __restrict__ Hadd,
                                                  const float* __restrict__ W,
                                                  const float* __restrict__ b,
                                                  float* __restrict__ C) {
    __shared__ float As[32][DIM];
    int row0 = blockIdx.x * 32;
    int tid = threadIdx.x;
    // stage A tile (+ optional h add): 32 rows * 32 float4
    for (int i = tid; i < 32 * 32; i += 256) {
        int r = i >> 5, c4 = i & 31;
        float4 v = make_float4(0.f, 0.f, 0.f, 0.f);
        if (row0 + r < NN) {
            v = *(const float4*)(A + (long long)(row0 + r) * DIM + c4 * 4);
            if (USEADD) {
                float4 hv = *(const float4*)(Hadd + (long long)(row0 + r) * DIM + c4 * 4);
                v.x += hv.x; v.y += hv.y; v.z += hv.z; v.w += hv.w;
            }
        }
        *(float4*)(&As[r][c4 * 4]) = v;
    }
    __syncthreads();
    int tx = tid & 31;   // col group (4 cols)
    int ty = tid >> 5;   // 0..7 row phase
    int c0 = tx * 4;
    float4 acc[4];
#pragma unroll
    for (int m = 0; m < 4; m++) acc[m] = make_float4(0.f, 0.f, 0.f, 0.f);
    for (int k = 0; k < DIM; k++) {
        float4 w = *(const float4*)(W + k * DIM + c0);
#pragma unroll
        for (int m = 0; m < 4; m++) {
            float a = As[ty + m * 8][k];
            acc[m].x += a * w.x;
            acc[m].y += a * w.y;
            acc[m].z += a * w.z;
            acc[m].w += a * w.w;
        }
    }
    float4 bias = *(const float4*)(b + c0);
#pragma unroll
    for (int m = 0; m < 4; m++) {
        int r = row0 + ty + m * 8;
        if (r >= NN) continue;
        float4 o;
        o.x = acc[m].x + bias.x;
        o.y = acc[m].y + bias.y;
        o.z = acc[m].z + bias.z;
        o.w = acc[m].w + bias.w;
        if (ACT) {
            o.x = lrelu(o.x); o.y = lrelu(o.y); o.z = lrelu(o.z); o.w = lrelu(o.w);
        }
        *(float4*)(C + (long long)r * DIM + c0) = o;
    }
}

// ---------------- BN stats: per-col sum & sumsq
__global__ __launch_bounds__(256) void bnstats_kernel(const float* __restrict__ Z,
                                                      float* __restrict__ stats) {
    int col = threadIdx.x & 127;
    int half = threadIdx.x >> 7;  // 0..1
    int stride = gridDim.x * 2;
    float s = 0.f, s2 = 0.f;
    for (int r = blockIdx.x * 2 + half; r < NN; r += stride) {
        float v = Z[(long long)r * DIM + col];
        s += v;
        s2 += v * v;
    }
    __shared__ float red[2][2][DIM];
    red[0][half][col] = s;
    red[1][half][col] = s2;
    __syncthreads();
    if (half == 0) {
        atomicAdd(&stats[col], red[0][0][col] + red[0][1][col]);
        atomicAdd(&stats[DIM + col], red[1][0][col] + red[1][1][col]);
    }
}

// ---------------- BN finalize: scale/shift per col
__global__ void bnfinalize_kernel(const float* __restrict__ stats,
                                  const float* __restrict__ gamma,
                                  const float* __restrict__ beta,
                                  float* __restrict__ ss) {
    int c = threadIdx.x;
    float mu = stats[c] * (1.f / NN);
    float var = stats[DIM + c] * (1.f / NN) - mu * mu;
    float sc = gamma[c] * rsqrtf(var + BN_EPS);
    ss[c] = sc;
    ss[DIM + c] = beta[c] - mu * sc;
}

// ---------------- BN apply (+ optional lrelu), elementwise float4
template <int ACT>
__global__ __launch_bounds__(256) void bnapply_kernel(const float* __restrict__ Z,
                                                      const float* __restrict__ ss,
                                                      float* __restrict__ H) {
    long long gid = (long long)blockIdx.x * blockDim.x + threadIdx.x;  // float4 units
    if (gid >= (long long)NN * 32) return;
    int c0 = (int)(gid & 31) * 4;
    float4 v = *(const float4*)(Z + gid * 4);
    float4 sc = *(const float4*)(ss + c0);
    float4 sh = *(const float4*)(ss + DIM + c0);
    float4 o;
    o.x = v.x * sc.x + sh.x;
    o.y = v.y * sc.y + sh.y;
    o.z = v.z * sc.z + sh.z;
    o.w = v.w * sc.w + sh.w;
    if (ACT) {
        o.x = lrelu(o.x); o.y = lrelu(o.y); o.z = lrelu(o.z); o.w = lrelu(o.w);
    }
    *(float4*)(H + gid * 4) = o;
}

// ---------------- gumbel softmax per node (wave per node) + pool atomics
__global__ __launch_bounds__(256) void softpool_kernel(const float* __restrict__ H,
                                                       const float* __restrict__ G,
                                                       const int* __restrict__ batch,
                                                       float* __restrict__ Cout,
                                                       float* __restrict__ pooled) {
    int node = blockIdx.x * 4 + (threadIdx.x >> 6);
    if (node >= NN) return;
    int lane = threadIdx.x & 63;
    long long base = (long long)node * DIM + lane * 2;
    float2 hv = *(const float2*)(H + base);
    float2 gv = *(const float2*)(G + base);
    float vx = hv.x + gv.x, vy = hv.y + gv.y;
    float m = fmaxf(vx, vy);
#pragma unroll
    for (int o = 32; o >= 1; o >>= 1) m = fmaxf(m, __shfl_xor(m, o));
    float ex = __expf(vx - m), ey = __expf(vy - m);
    float s = ex + ey;
#pragma unroll
    for (int o = 32; o >= 1; o >>= 1) s += __shfl_xor(s, o);
    float inv = 1.f / s;
    float2 c;
    c.x = ex * inv;
    c.y = ey * inv;
    *(float2*)(Cout + base) = c;
    int g = batch[node];
    atomicAdd(&pooled[g * DIM + lane * 2], c.x);
    atomicAdd(&pooled[g * DIM + lane * 2 + 1], c.y);
}

// ---------------- dense head: one block per graph
__global__ __launch_bounds__(128) void head_kernel(const float* __restrict__ pooled,
                                                   const float* __restrict__ Wd1,
                                                   const float* __restrict__ bd1,
                                                   const float* __restrict__ Wd2,
                                                   const float* __restrict__ bd2,
                                                   float* __restrict__ out) {
    int g = blockIdx.x;
    int j = threadIdx.x;  // 0..127
    __shared__ float hid[DIM];
    __shared__ float logits[NCLASSES];
    float acc = bd1[j];
    for (int k = 0; k < DIM; k++) acc += pooled[g * DIM + k] * Wd1[k * DIM + j];
    hid[j] = lrelu(acc);
    __syncthreads();
    if (j < NCLASSES) {
        float a = bd2[j];
        for (int k = 0; k < DIM; k++) a += hid[k] * Wd2[k * NCLASSES + j];
        logits[j] = a;
    }
    __syncthreads();
    if (j == 0) {
        float m = -1e30f;
        for (int c = 0; c < NCLASSES; c++) m = fmaxf(m, logits[c]);
        float s = 0.f, e[NCLASSES];
        for (int c = 0; c < NCLASSES; c++) { e[c] = __expf(logits[c] - m); s += e[c]; }
        float inv = 1.f / s;
        for (int c = 0; c < NCLASSES; c++) out[g * NCLASSES + c] = e[c] * inv;
    }
}

extern "C" void kernel_launch(void* const* d_in, const int* in_sizes, int n_in,
                              void* d_out, int out_size, void* d_ws, size_t ws_size,
                              hipStream_t stream) {
    const float* x = (const float*)d_in[0];
    const int* edges = (const int*)d_in[1];
    const int* batch = (const int*)d_in[2];
    const float* gum = (const float*)d_in[3];
    const float* W1s = (const float*)d_in[4];
    const float* b1s = (const float*)d_in[5];
    const float* W2s = (const float*)d_in[6];
    const float* b2s = (const float*)d_in[7];
    const float* gammas = (const float*)d_in[8];
    const float* betas = (const float*)d_in[9];
    const float* Wd1 = (const float*)d_in[10];
    const float* bd1 = (const float*)d_in[11];
    const float* Wd2 = (const float*)d_in[12];
    const float* bd2 = (const float*)d_in[13];

    float* out = (float*)d_out;
    float* cout = out + NGRAPHS * NCLASSES;

    const size_t ND = (size_t)NN * DIM;
    float* ws = (float*)d_ws;
    float* h0 = ws;
    float* h1 = h0 + ND;
    float* agg = h1 + ND;
    float* stats = agg + ND;        // 2*DIM
    float* ss = stats + 2 * DIM;    // 2*DIM
    float* pooled = ss + 2 * DIM;   // NGRAPHS*DIM

    const int GEMM_BLOCKS = (NN + 31) / 32;

    for (int i = 0; i < NLAYERS; i++) {
        const float* hr = (i == 0) ? x : ((i & 1) ? h0 : h1);
        float* hw = (i & 1) ? h1 : h0;
        const float* W1 = W1s + (size_t)i * DIM * DIM;
        const float* b1 = b1s + (size_t)i * DIM;
        const float* W2 = W2s + (size_t)i * DIM * DIM;
        const float* b2 = b2s + (size_t)i * DIM;

        hipMemsetAsync(agg, 0, ND * sizeof(float), stream);
        scatter_kernel<<<(int)(((long long)NE * 32 + 255) / 256), 256, 0, stream>>>(hr, edges, agg);
        // z1 = lrelu((h + agg) @ W1 + b1)  -> hw
        gemm_fused<1, 1><<<GEMM_BLOCKS, 256, 0, stream>>>(agg, hr, W1, b1, hw);
        // z2 = z1 @ W2 + b2 -> agg (reuse)
        gemm_fused<0, 0><<<GEMM_BLOCKS, 256, 0, stream>>>(hw, nullptr, W2, b2, agg);
        hipMemsetAsync(stats, 0, 2 * DIM * sizeof(float), stream);
        bnstats_kernel<<<512, 256, 0, stream>>>(agg, stats);
        bnfinalize_kernel<<<1, DIM, 0, stream>>>(stats, gammas + (size_t)i * DIM,
                                                 betas + (size_t)i * DIM, ss);
        if (i < NLAYERS - 1)
            bnapply_kernel<1><<<(int)((ND / 4 + 255) / 256), 256, 0, stream>>>(agg, ss, hw);
        else
            bnapply_kernel<0><<<(int)((ND / 4 + 255) / 256), 256, 0, stream>>>(agg, ss, hw);
    }

    hipMemsetAsync(pooled, 0, NGRAPHS * DIM * sizeof(float), stream);
    // final h is in h1 (layer 7 wrote h1)
    softpool_kernel<<<(NN + 3) / 4, 256, 0, stream>>>(h1, gum, batch, cout, pooled);
    head_kernel<<<NGRAPHS, 128, 0, stream>>>(pooled, Wd1, bd1, Wd2, bd2, out);
}

// Round 5
// 1637.444 us; speedup vs baseline: 5.5870x; 5.5870x over previous
//
#include <hip/hip_runtime.h>

#define NN 50000
#define NE 600000
#define DIM 128
#define NLAYERS 8
#define NCLASSES 10
#define NGRAPHS 64
#define BN_EPS 1e-5f
#define SLOPE 0.01f

__device__ __forceinline__ float lrelu(float v) { return v > 0.f ? v : SLOPE * v; }

// ---------------- CSR build: degree histogram
__global__ __launch_bounds__(256) void degree_kernel(const int* __restrict__ edges,
                                                     int* __restrict__ counts) {
    int e = blockIdx.x * 256 + threadIdx.x;
    if (e >= NE) return;
    atomicAdd(&counts[edges[NE + e]], 1);
}

// ---------------- CSR build: exclusive scan of counts -> offsets (single block, 1024 thr)
__global__ __launch_bounds__(1024) void scan_kernel(const int* __restrict__ counts,
                                                    int* __restrict__ offsets) {
    __shared__ int wsum[16];
    __shared__ int carry;
    int lane = threadIdx.x & 63, wid = threadIdx.x >> 6;
    if (threadIdx.x == 0) { carry = 0; offsets[0] = 0; }
    __syncthreads();
    for (int base = 0; base < NN; base += 1024) {
        int i = base + threadIdx.x;
        int v = (i < NN) ? counts[i] : 0;
        int s = v;
#pragma unroll
        for (int o = 1; o < 64; o <<= 1) {
            int t = __shfl_up(s, o);
            if (lane >= o) s += t;
        }
        if (lane == 63) wsum[wid] = s;
        __syncthreads();
        if (wid == 0 && lane < 16) {
            int w = wsum[lane];
            int sw = w;
#pragma unroll
            for (int o = 1; o < 16; o <<= 1) {
                int t = __shfl_up(sw, o);
                if (lane >= o) sw += t;
            }
            wsum[lane] = sw - w;  // exclusive
        }
        __syncthreads();
        int incl = s + wsum[wid] + carry;
        if (i < NN) offsets[i + 1] = incl;
        __syncthreads();
        if (threadIdx.x == 1023) carry = incl;
        __syncthreads();
    }
}

// ---------------- CSR build: fill src lists
__global__ __launch_bounds__(256) void fill_kernel(const int* __restrict__ edges,
                                                   int* __restrict__ cursor,
                                                   int* __restrict__ csr_src) {
    int e = blockIdx.x * 256 + threadIdx.x;
    if (e >= NE) return;
    int d = edges[NE + e];
    int p = atomicAdd(&cursor[d], 1);
    csr_src[p] = edges[e];
}

// ---------------- gather: hz[i] = h[i] + sum_{j in N(i)} h[j]   (wave per node)
__global__ __launch_bounds__(256) void gather_kernel(const float* __restrict__ h,
                                                     const int* __restrict__ offsets,
                                                     const int* __restrict__ csr_src,
                                                     float* __restrict__ hz) {
    int node = blockIdx.x * 4 + (threadIdx.x >> 6);
    if (node >= NN) return;
    int lane = threadIdx.x & 63;
    int beg = offsets[node], end = offsets[node + 1];
    float2 acc = *(const float2*)(h + (size_t)node * DIM + lane * 2);
    for (int e = beg; e < end; e++) {
        int s = csr_src[e];
        float2 v = *(const float2*)(h + (size_t)s * DIM + lane * 2);
        acc.x += v.x;
        acc.y += v.y;
    }
    *(float2*)(hz + (size_t)node * DIM + lane * 2) = acc;
}

// ---------------- fused GEMM: C = act( A @ W + b ),  A:[NN,128] W:[128,128]
template <int ACT>
__global__ __launch_bounds__(256) void gemm_fused(const float* __restrict__ A,
                                                  const float* __restrict__ W,
                                                  const float* __restrict__ b,
                                                  float* __restrict__ C) {
    __shared__ float As[32][DIM];
    int row0 = blockIdx.x * 32;
    int tid = threadIdx.x;
    for (int i = tid; i < 32 * 32; i += 256) {
        int r = i >> 5, c4 = i & 31;
        float4 v = make_float4(0.f, 0.f, 0.f, 0.f);
        if (row0 + r < NN) v = *(const float4*)(A + (long long)(row0 + r) * DIM + c4 * 4);
        *(float4*)(&As[r][c4 * 4]) = v;
    }
    __syncthreads();
    int tx = tid & 31;
    int ty = tid >> 5;
    int c0 = tx * 4;
    float4 acc[4];
#pragma unroll
    for (int m = 0; m < 4; m++) acc[m] = make_float4(0.f, 0.f, 0.f, 0.f);
    for (int k = 0; k < DIM; k++) {
        float4 w = *(const float4*)(W + k * DIM + c0);
#pragma unroll
        for (int m = 0; m < 4; m++) {
            float a = As[ty + m * 8][k];
            acc[m].x += a * w.x;
            acc[m].y += a * w.y;
            acc[m].z += a * w.z;
            acc[m].w += a * w.w;
        }
    }
    float4 bias = *(const float4*)(b + c0);
#pragma unroll
    for (int m = 0; m < 4; m++) {
        int r = row0 + ty + m * 8;
        if (r >= NN) continue;
        float4 o;
        o.x = acc[m].x + bias.x;
        o.y = acc[m].y + bias.y;
        o.z = acc[m].z + bias.z;
        o.w = acc[m].w + bias.w;
        if (ACT) { o.x = lrelu(o.x); o.y = lrelu(o.y); o.z = lrelu(o.z); o.w = lrelu(o.w); }
        *(float4*)(C + (long long)r * DIM + c0) = o;
    }
}

// ---------------- BN stats
__global__ __launch_bounds__(256) void bnstats_kernel(const float* __restrict__ Z,
                                                      float* __restrict__ stats) {
    int col = threadIdx.x & 127;
    int half = threadIdx.x >> 7;
    int stride = gridDim.x * 2;
    float s = 0.f, s2 = 0.f;
    for (int r = blockIdx.x * 2 + half; r < NN; r += stride) {
        float v = Z[(long long)r * DIM + col];
        s += v;
        s2 += v * v;
    }
    __shared__ float red[2][2][DIM];
    red[0][half][col] = s;
    red[1][half][col] = s2;
    __syncthreads();
    if (half == 0) {
        atomicAdd(&stats[col], red[0][0][col] + red[0][1][col]);
        atomicAdd(&stats[DIM + col], red[1][0][col] + red[1][1][col]);
    }
}

__global__ void bnfinalize_kernel(const float* __restrict__ stats,
                                  const float* __restrict__ gamma,
                                  const float* __restrict__ beta,
                                  float* __restrict__ ss) {
    int c = threadIdx.x;
    float mu = stats[c] * (1.f / NN);
    float var = stats[DIM + c] * (1.f / NN) - mu * mu;
    float sc = gamma[c] * rsqrtf(var + BN_EPS);
    ss[c] = sc;
    ss[DIM + c] = beta[c] - mu * sc;
}

template <int ACT>
__global__ __launch_bounds__(256) void bnapply_kernel(const float* __restrict__ Z,
                                                      const float* __restrict__ ss,
                                                      float* __restrict__ H) {
    long long gid = (long long)blockIdx.x * blockDim.x + threadIdx.x;
    if (gid >= (long long)NN * 32) return;
    int c0 = (int)(gid & 31) * 4;
    float4 v = *(const float4*)(Z + gid * 4);
    float4 sc = *(const float4*)(ss + c0);
    float4 sh = *(const float4*)(ss + DIM + c0);
    float4 o;
    o.x = v.x * sc.x + sh.x;
    o.y = v.y * sc.y + sh.y;
    o.z = v.z * sc.z + sh.z;
    o.w = v.w * sc.w + sh.w;
    if (ACT) { o.x = lrelu(o.x); o.y = lrelu(o.y); o.z = lrelu(o.z); o.w = lrelu(o.w); }
    *(float4*)(H + gid * 4) = o;
}

// ---------------- gumbel softmax + pool
__global__ __launch_bounds__(256) void softpool_kernel(const float* __restrict__ H,
                                                       const float* __restrict__ G,
                                                       const int* __restrict__ batch,
                                                       float* __restrict__ Cout,
                                                       float* __restrict__ pooled) {
    int node = blockIdx.x * 4 + (threadIdx.x >> 6);
    if (node >= NN) return;
    int lane = threadIdx.x & 63;
    long long base = (long long)node * DIM + lane * 2;
    float2 hv = *(const float2*)(H + base);
    float2 gv = *(const float2*)(G + base);
    float vx = hv.x + gv.x, vy = hv.y + gv.y;
    float m = fmaxf(vx, vy);
#pragma unroll
    for (int o = 32; o >= 1; o >>= 1) m = fmaxf(m, __shfl_xor(m, o));
    float ex = __expf(vx - m), ey = __expf(vy - m);
    float s = ex + ey;
#pragma unroll
    for (int o = 32; o >= 1; o >>= 1) s += __shfl_xor(s, o);
    float inv = 1.f / s;
    float2 c;
    c.x = ex * inv;
    c.y = ey * inv;
    *(float2*)(Cout + base) = c;
    int g = batch[node];
    atomicAdd(&pooled[g * DIM + lane * 2], c.x);
    atomicAdd(&pooled[g * DIM + lane * 2 + 1], c.y);
}

// ---------------- dense head
__global__ __launch_bounds__(128) void head_kernel(const float* __restrict__ pooled,
                                                   const float* __restrict__ Wd1,
                                                   const float* __restrict__ bd1,
                                                   const float* __restrict__ Wd2,
                                                   const float* __restrict__ bd2,
                                                   float* __restrict__ out) {
    int g = blockIdx.x;
    int j = threadIdx.x;
    __shared__ float hid[DIM];
    __shared__ float logits[NCLASSES];
    float acc = bd1[j];
    for (int k = 0; k < DIM; k++) acc += pooled[g * DIM + k] * Wd1[k * DIM + j];
    hid[j] = lrelu(acc);
    __syncthreads();
    if (j < NCLASSES) {
        float a = bd2[j];
        for (int k = 0; k < DIM; k++) a += hid[k] * Wd2[k * NCLASSES + j];
        logits[j] = a;
    }
    __syncthreads();
    if (j == 0) {
        float m = -1e30f;
        for (int c = 0; c < NCLASSES; c++) m = fmaxf(m, logits[c]);
        float s = 0.f, e[NCLASSES];
        for (int c = 0; c < NCLASSES; c++) { e[c] = __expf(logits[c] - m); s += e[c]; }
        float inv = 1.f / s;
        for (int c = 0; c < NCLASSES; c++) out[g * NCLASSES + c] = e[c] * inv;
    }
}

extern "C" void kernel_launch(void* const* d_in, const int* in_sizes, int n_in,
                              void* d_out, int out_size, void* d_ws, size_t ws_size,
                              hipStream_t stream) {
    const float* x = (const float*)d_in[0];
    const int* edges = (const int*)d_in[1];
    const int* batch = (const int*)d_in[2];
    const float* gum = (const float*)d_in[3];
    const float* W1s = (const float*)d_in[4];
    const float* b1s = (const float*)d_in[5];
    const float* W2s = (const float*)d_in[6];
    const float* b2s = (const float*)d_in[7];
    const float* gammas = (const float*)d_in[8];
    const float* betas = (const float*)d_in[9];
    const float* Wd1 = (const float*)d_in[10];
    const float* bd1 = (const float*)d_in[11];
    const float* Wd2 = (const float*)d_in[12];
    const float* bd2 = (const float*)d_in[13];

    float* out = (float*)d_out;
    float* cout = out + NGRAPHS * NCLASSES;

    const size_t ND = (size_t)NN * DIM;
    float* ws = (float*)d_ws;
    float* h0 = ws;
    float* h1 = h0 + ND;
    float* agg = h1 + ND;
    float* stats = agg + ND;         // 2*DIM
    float* ss = stats + 2 * DIM;     // 2*DIM
    float* pooled = ss + 2 * DIM;    // NGRAPHS*DIM
    int* counts = (int*)(pooled + NGRAPHS * DIM);  // NN
    int* offsets = counts + NN;                    // NN+1
    int* cursor = offsets + NN + 1;                // NN
    int* csr_src = cursor + NN;                    // NE

    const int GEMM_BLOCKS = (NN + 31) / 32;
    const int EDGE_BLOCKS = (NE + 255) / 256;
    const int NODE_BLOCKS = (NN + 3) / 4;

    // ---- CSR build (once per launch; structure is static across layers)
    hipMemsetAsync(counts, 0, NN * sizeof(int), stream);
    degree_kernel<<<EDGE_BLOCKS, 256, 0, stream>>>(edges, counts);
    scan_kernel<<<1, 1024, 0, stream>>>(counts, offsets);
    hipMemcpyAsync(cursor, offsets, NN * sizeof(int), hipMemcpyDeviceToDevice, stream);
    fill_kernel<<<EDGE_BLOCKS, 256, 0, stream>>>(edges, cursor, csr_src);

    for (int i = 0; i < NLAYERS; i++) {
        const float* hr = (i == 0) ? x : ((i & 1) ? h0 : h1);
        float* hw = (i & 1) ? h1 : h0;
        const float* W1 = W1s + (size_t)i * DIM * DIM;
        const float* b1 = b1s + (size_t)i * DIM;
        const float* W2 = W2s + (size_t)i * DIM * DIM;
        const float* b2 = b2s + (size_t)i * DIM;

        // hz = h + sum_neighbors(h)  -> agg
        gather_kernel<<<NODE_BLOCKS, 256, 0, stream>>>(hr, offsets, csr_src, agg);
        // z1 = lrelu(hz @ W1 + b1) -> hw
        gemm_fused<1><<<GEMM_BLOCKS, 256, 0, stream>>>(agg, W1, b1, hw);
        // z2 = z1 @ W2 + b2 -> agg
        gemm_fused<0><<<GEMM_BLOCKS, 256, 0, stream>>>(hw, W2, b2, agg);
        hipMemsetAsync(stats, 0, 2 * DIM * sizeof(float), stream);
        bnstats_kernel<<<512, 256, 0, stream>>>(agg, stats);
        bnfinalize_kernel<<<1, DIM, 0, stream>>>(stats, gammas + (size_t)i * DIM,
                                                 betas + (size_t)i * DIM, ss);
        if (i < NLAYERS - 1)
            bnapply_kernel<1><<<(int)((ND / 4 + 255) / 256), 256, 0, stream>>>(agg, ss, hw);
        else
            bnapply_kernel<0><<<(int)((ND / 4 + 255) / 256), 256, 0, stream>>>(agg, ss, hw);
    }

    hipMemsetAsync(pooled, 0, NGRAPHS * DIM * sizeof(float), stream);
    softpool_kernel<<<NODE_BLOCKS, 256, 0, stream>>>(h1, gum, batch, cout, pooled);
    head_kernel<<<NGRAPHS, 128, 0, stream>>>(pooled, Wd1, bd1, Wd2, bd2, out);
}